// Round 1
// baseline (2723.086 us; speedup 1.0000x reference)
//
#include <hip/hip_runtime.h>

#define S 207
#define BATCH 128
#define NPTS 256000

// bn slice offsets: cumsum of SIZES
__constant__ int dummy_unused[1];
static const int OFFS[19] = {0,8,16,24,32,40,56,72,88,104,128,152,176,200,232,264,296,328,392};

__global__ void zero2_kernel(float* __restrict__ a, float* __restrict__ b, int n) {
    int i = blockIdx.x * blockDim.x + threadIdx.x;
    if (i < n) { a[i] = 0.0f; b[i] = 0.0f; }
}

__global__ void scatter_kernel(const int* __restrict__ loc, const int* __restrict__ bidx,
                               const float* __restrict__ feat,
                               float* __restrict__ xs, float* __restrict__ ms) {
    int t = blockIdx.x * blockDim.x + threadIdx.x;
    if (t >= NPTS) return;
    int b = bidx[t];
    int r = loc[2 * t];
    int c = loc[2 * t + 1];
    int idx = (b * S + r) * S + c;
    atomicAdd(&xs[idx], feat[t]);
    ms[idx] = 1.0f;   // .at[idx].set(1.0) — duplicates all write 1
}

// Fused: x=conv(xs,conv0,SAME)*m ; m2=maxpool(m,3,2) ; x=where(m2>0, maxpool(where(m>0,x,NEG)), 0)
// Output 103x103x8 + mask. Computes conv0 at the 9 window positions on the fly.
__global__ void conv0_pool_kernel(const float* __restrict__ xs, const float* __restrict__ ms,
                                  const float* __restrict__ w,   // (3,3,1,8) HWIO
                                  float* __restrict__ x1, float* __restrict__ m1) {
    const int Hout = 103, Wout = 103;
    int tid = blockIdx.x * blockDim.x + threadIdx.x;
    int total = BATCH * Hout * Wout * 8;
    if (tid >= total) return;
    int co = tid & 7;
    int p = tid >> 3;
    int wo = p % Wout; p /= Wout;
    int ho = p % Hout;
    int b  = p / Hout;
    float best = -1e30f;
    float mwin = 0.0f;
    for (int pi = 0; pi < 3; ++pi) {
        int ii = 2 * ho + pi;            // <= 206, always in range
        for (int pj = 0; pj < 3; ++pj) {
            int jj = 2 * wo + pj;
            float mv = ms[(b * S + ii) * S + jj];
            if (mv > 0.0f) {
                mwin = 1.0f;
                float acc = 0.0f;
                #pragma unroll
                for (int kh = 0; kh < 3; ++kh) {
                    int r = ii + kh - 1;
                    if ((unsigned)r >= (unsigned)S) continue;
                    #pragma unroll
                    for (int kw = 0; kw < 3; ++kw) {
                        int cc = jj + kw - 1;
                        if ((unsigned)cc >= (unsigned)S) continue;
                        acc += xs[(b * S + r) * S + cc] * w[(kh * 3 + kw) * 8 + co];
                    }
                }
                best = fmaxf(best, acc);
            }
        }
    }
    x1[tid] = (mwin > 0.0f) ? best : 0.0f;
    if (co == 0) m1[(b * Hout + ho) * Wout + wo] = mwin;
}

// Direct conv NHWC, HWIO weights, out = conv(in)*mask [+ res]
template <int K, int CIN, int COUT>
__global__ void conv_kernel(const float* __restrict__ in, const float* __restrict__ w,
                            const float* __restrict__ mask, const float* __restrict__ res,
                            float* __restrict__ out,
                            int Hin, int Win, int Hout, int Wout, int stride, int pad) {
    int tid = blockIdx.x * blockDim.x + threadIdx.x;
    int total = BATCH * Hout * Wout * COUT;
    if (tid >= total) return;
    int co = tid % COUT;
    int p = tid / COUT;
    int wo = p % Wout; p /= Wout;
    int ho = p % Hout;
    int b  = p / Hout;
    float acc = 0.0f;
    #pragma unroll
    for (int kh = 0; kh < K; ++kh) {
        int ih = ho * stride + kh - pad;
        if ((unsigned)ih >= (unsigned)Hin) continue;
        #pragma unroll
        for (int kw = 0; kw < K; ++kw) {
            int iw = wo * stride + kw - pad;
            if ((unsigned)iw >= (unsigned)Win) continue;
            const float* ip = in + ((b * Hin + ih) * Win + iw) * CIN;
            const float* wp = w + (kh * K + kw) * CIN * COUT + co;
            #pragma unroll
            for (int ci = 0; ci < CIN; ++ci)
                acc += ip[ci] * wp[ci * COUT];
        }
    }
    float o = acc * mask[(b * Hout + ho) * Wout + wo];
    if (res) o += res[tid];
    out[tid] = o;
}

__global__ void bnrelu_kernel(const float* __restrict__ in, const float* __restrict__ mask,
                              const float* __restrict__ g, const float* __restrict__ bb,
                              float* __restrict__ out, int total, int C) {
    int tid = blockIdx.x * blockDim.x + threadIdx.x;
    if (tid >= total) return;
    int c = tid % C;
    int pix = tid / C;
    float v = fmaf(in[tid], g[c], bb[c]);
    out[tid] = mask[pix] * fmaxf(v, 0.0f);
}

__global__ void pool_kernel(const float* __restrict__ in, float* __restrict__ out,
                            int Hin, int Win, int Hout, int Wout, int win, int stride) {
    int tid = blockIdx.x * blockDim.x + threadIdx.x;
    int total = BATCH * Hout * Wout;
    if (tid >= total) return;
    int wo = tid % Wout;
    int p = tid / Wout;
    int ho = p % Hout;
    int b  = p / Hout;
    float mx = 0.0f;   // reference pool init 0.0
    for (int i = 0; i < win; ++i)
        for (int j = 0; j < win; ++j)
            mx = fmaxf(mx, in[(b * Hin + ho * stride + i) * Win + wo * stride + j]);
    out[tid] = mx;
}

// x: (B,8,8,64) NHWC; flat (NCHW order) k = c*64 + h*8 + w; wl: (100,4096)
__global__ void linear_kernel(const float* __restrict__ x, const float* __restrict__ wl,
                              float* __restrict__ out) {
    int tid = blockIdx.x * blockDim.x + threadIdx.x;
    if (tid >= BATCH * 100) return;
    int o = tid % 100;
    int b = tid / 100;
    const float* wr = wl + o * 4096;
    float acc = 0.0f;
    for (int c = 0; c < 64; ++c)
        for (int h = 0; h < 8; ++h)
            #pragma unroll
            for (int w = 0; w < 8; ++w)
                acc += x[((b * 8 + h) * 8 + w) * 64 + c] * wr[c * 64 + h * 8 + w];
    out[tid] = acc;
}

template <int K, int CIN, int COUT>
static inline void conv_launch(hipStream_t s, const float* in, const float* w,
                               const float* mask, const float* res, float* out,
                               int Hin, int Hout, int stride, int pad) {
    int total = BATCH * Hout * Hout * COUT;
    conv_kernel<K, CIN, COUT><<<(total + 255) / 256, 256, 0, s>>>(
        in, w, mask, res, out, Hin, Hin, Hout, Hout, stride, pad);
}

extern "C" void kernel_launch(void* const* d_in, const int* in_sizes, int n_in,
                              void* d_out, int out_size, void* d_ws, size_t ws_size,
                              hipStream_t stream) {
    const int*   loc   = (const int*)d_in[0];
    const int*   bidx  = (const int*)d_in[1];
    const float* feat  = (const float*)d_in[2];
    const float* gamma = (const float*)d_in[3];
    const float* beta  = (const float*)d_in[4];
    const float* Wconv0 = (const float*)d_in[5];
    const float* Wc1a = (const float*)d_in[6];
    const float* Wc1b = (const float*)d_in[7];
    const float* Wc2a = (const float*)d_in[8];
    const float* Wc2b = (const float*)d_in[9];
    const float* Wc3a = (const float*)d_in[10];
    const float* Wc3b = (const float*)d_in[11];
    const float* Wc3r = (const float*)d_in[12];
    const float* Wc4a = (const float*)d_in[13];
    const float* Wc4b = (const float*)d_in[14];
    const float* Wc5a = (const float*)d_in[15];
    const float* Wc5b = (const float*)d_in[16];
    const float* Wc5r = (const float*)d_in[17];
    const float* Wc6a = (const float*)d_in[18];
    const float* Wc6b = (const float*)d_in[19];
    const float* Wc7a = (const float*)d_in[20];
    const float* Wc7b = (const float*)d_in[21];
    const float* Wc7r = (const float*)d_in[22];
    const float* Wc8a = (const float*)d_in[23];
    const float* Wc8b = (const float*)d_in[24];
    const float* Wlast = (const float*)d_in[25];
    const float* wlin  = (const float*)d_in[26];

    // Workspace arena (floats): 3 ping-pong activation buffers + 2 mask buffers.
    // 3*10,863,616 + 2*1,357,952 = 35,306,752 floats = 141.2 MB
    const size_t SZB = (size_t)BATCH * 103 * 103 * 8;  // 10,863,616
    const size_t SZM = (size_t)BATCH * 103 * 103;      // 1,357,952
    float* b0 = (float*)d_ws;
    float* b1 = b0 + SZB;
    float* b2 = b1 + SZB;
    float* m0 = b2 + SZB;
    float* m1 = m0 + SZM;

    const float* G[18];
    const float* Bt[18];
    for (int i = 0; i < 18; ++i) { G[i] = gamma + OFFS[i]; Bt[i] = beta + OFFS[i]; }

    auto bnrelu = [&](const float* in, const float* mask, int gi, float* out, int H, int C) {
        int total = BATCH * H * H * C;
        bnrelu_kernel<<<(total + 255) / 256, 256, 0, stream>>>(in, mask, G[gi], Bt[gi], out, total, C);
    };
    auto pool = [&](const float* in, float* out, int Hin, int Hout, int win, int stride_) {
        int total = BATCH * Hout * Hout;
        pool_kernel<<<(total + 255) / 256, 256, 0, stream>>>(in, out, Hin, Hin, Hout, Hout, win, stride_);
    };

    // ---- scatter into xs(b1), ms(b2) (zero-init first: ws is poisoned 0xAA) ----
    {
        int n = BATCH * S * S;
        zero2_kernel<<<(n + 255) / 256, 256, 0, stream>>>(b1, b2, n);
        scatter_kernel<<<(NPTS + 255) / 256, 256, 0, stream>>>(loc, bidx, feat, b1, b2);
        int total = BATCH * 103 * 103 * 8;
        conv0_pool_kernel<<<(total + 255) / 256, 256, 0, stream>>>(b1, b2, Wconv0, b0, m0);
    }
    // x = b0 (103,103,8), mask = m0

    // ---- block c1 (stride1, H=103, C=8) ----
    bnrelu(b0, m0, 0, b1, 103, 8);
    conv_launch<3, 8, 8>(stream, b1, Wc1a, m0, nullptr, b2, 103, 103, 1, 1);
    bnrelu(b2, m0, 1, b1, 103, 8);
    conv_launch<3, 8, 8>(stream, b1, Wc1b, m0, b0, b2, 103, 103, 1, 1);
    // x = b2
    // ---- block c2 ----
    bnrelu(b2, m0, 2, b0, 103, 8);
    conv_launch<3, 8, 8>(stream, b0, Wc2a, m0, nullptr, b1, 103, 103, 1, 1);
    bnrelu(b1, m0, 3, b0, 103, 8);
    conv_launch<3, 8, 8>(stream, b0, Wc2b, m0, b2, b1, 103, 103, 1, 1);
    // x = b1
    // ---- block c3 (stride2, 103->51, 8->16) ----
    pool(m0, m1, 103, 51, 3, 2);
    bnrelu(b1, m0, 4, b0, 103, 8);
    conv_launch<3, 8, 16>(stream, b0, Wc3a, m1, nullptr, b2, 103, 51, 2, 0);
    bnrelu(b2, m1, 5, b0, 51, 16);
    conv_launch<3, 8, 16>(stream, b1, Wc3r, m1, nullptr, b2, 103, 51, 2, 0);
    conv_launch<3, 16, 16>(stream, b0, Wc3b, m1, b2, b1, 51, 51, 1, 1);
    // x = b1, mask = m1
    // ---- block c4 (stride1, 51, C=16) ----
    bnrelu(b1, m1, 6, b0, 51, 16);
    conv_launch<3, 16, 16>(stream, b0, Wc4a, m1, nullptr, b2, 51, 51, 1, 1);
    bnrelu(b2, m1, 7, b0, 51, 16);
    conv_launch<3, 16, 16>(stream, b0, Wc4b, m1, b1, b2, 51, 51, 1, 1);
    // x = b2
    // ---- block c5 (stride2, 51->25, 16->24) ----
    pool(m1, m0, 51, 25, 3, 2);
    bnrelu(b2, m1, 8, b0, 51, 16);
    conv_launch<3, 16, 24>(stream, b0, Wc5a, m0, nullptr, b1, 51, 25, 2, 0);
    bnrelu(b1, m0, 9, b0, 25, 24);
    conv_launch<3, 16, 24>(stream, b2, Wc5r, m0, nullptr, b1, 51, 25, 2, 0);
    conv_launch<3, 24, 24>(stream, b0, Wc5b, m0, b1, b2, 25, 25, 1, 1);
    // x = b2, mask = m0
    // ---- block c6 (stride1, 25, C=24) ----
    bnrelu(b2, m0, 10, b0, 25, 24);
    conv_launch<3, 24, 24>(stream, b0, Wc6a, m0, nullptr, b1, 25, 25, 1, 1);
    bnrelu(b1, m0, 11, b0, 25, 24);
    conv_launch<3, 24, 24>(stream, b0, Wc6b, m0, b2, b1, 25, 25, 1, 1);
    // x = b1
    // ---- block c7 (stride2, 25->12, 24->32) ----
    pool(m0, m1, 25, 12, 3, 2);
    bnrelu(b1, m0, 12, b0, 25, 24);
    conv_launch<3, 24, 32>(stream, b0, Wc7a, m1, nullptr, b2, 25, 12, 2, 0);
    bnrelu(b2, m1, 13, b0, 12, 32);
    conv_launch<3, 24, 32>(stream, b1, Wc7r, m1, nullptr, b2, 25, 12, 2, 0);
    conv_launch<3, 32, 32>(stream, b0, Wc7b, m1, b2, b1, 12, 12, 1, 1);
    // x = b1, mask = m1
    // ---- block c8 (stride1, 12, C=32) ----
    bnrelu(b1, m1, 14, b0, 12, 32);
    conv_launch<3, 32, 32>(stream, b0, Wc8a, m1, nullptr, b2, 12, 12, 1, 1);
    bnrelu(b2, m1, 15, b0, 12, 32);
    conv_launch<3, 32, 32>(stream, b0, Wc8b, m1, b1, b2, 12, 12, 1, 1);
    // x = b2
    // ---- tail: bnrelu, 5x5 strided conv_last, bnrelu, linear ----
    bnrelu(b2, m1, 16, b0, 12, 32);
    pool(m1, m0, 12, 8, 5, 1);
    conv_launch<5, 32, 64>(stream, b0, Wlast, m0, nullptr, b1, 12, 8, 1, 0);
    bnrelu(b1, m0, 17, b2, 8, 64);
    linear_kernel<<<(BATCH * 100 + 255) / 256, 256, 0, stream>>>(b2, wlin, (float*)d_out);
}

// Round 2
// 981.705 us; speedup vs baseline: 2.7738x; 2.7738x over previous
//
#include <hip/hip_runtime.h>

#define S 207
#define BATCH 128
#define NPTS 256000

static const int OFFS[19] = {0,8,16,24,32,40,56,72,88,104,128,152,176,200,232,264,296,328,392};

__global__ void zero2_kernel(float4* __restrict__ a, float4* __restrict__ b, int n4) {
    int i = blockIdx.x * blockDim.x + threadIdx.x;
    if (i < n4) { a[i] = make_float4(0,0,0,0); b[i] = make_float4(0,0,0,0); }
}

__global__ void scatter_kernel(const int* __restrict__ loc, const int* __restrict__ bidx,
                               const float* __restrict__ feat,
                               float* __restrict__ xs, float* __restrict__ ms) {
    int t = blockIdx.x * blockDim.x + threadIdx.x;
    if (t >= NPTS) return;
    int b = bidx[t];
    int r = loc[2 * t];
    int c = loc[2 * t + 1];
    int idx = (b * S + r) * S + c;
    atomicAdd(&xs[idx], feat[t]);
    ms[idx] = 1.0f;
}

// Fused conv0(SAME)*m -> masked 3x2 maxpool. One thread per output pixel, all 8 channels.
__global__ __launch_bounds__(256) void conv0_pool_kernel(
    const float* __restrict__ xs, const float* __restrict__ ms,
    const float* __restrict__ w,   // (3,3,1,8)
    float* __restrict__ x1, float* __restrict__ m1) {
    const int Hout = 103;
    int opix = blockIdx.x * 256 + threadIdx.x;
    int total = BATCH * Hout * Hout;
    if (opix >= total) return;
    int wo = opix % Hout;
    int t = opix / Hout;
    int ho = t % Hout;
    int b  = t / Hout;

    float mv[3][3];
    float mwin = 0.0f;
    #pragma unroll
    for (int pi = 0; pi < 3; ++pi)
        #pragma unroll
        for (int pj = 0; pj < 3; ++pj) {
            float m = ms[(b * S + 2 * ho + pi) * S + 2 * wo + pj];
            mv[pi][pj] = m;
            mwin = fmaxf(mwin, m);
        }
    float* xp = x1 + (size_t)opix * 8;
    if (mwin <= 0.0f) {
        *(float4*)xp = make_float4(0,0,0,0);
        *(float4*)(xp + 4) = make_float4(0,0,0,0);
        m1[opix] = 0.0f;
        return;
    }
    // 5x5 input patch centered on the pool window (rows 2ho-1..2ho+3)
    float p[5][5];
    #pragma unroll
    for (int r = 0; r < 5; ++r) {
        int ii = 2 * ho - 1 + r;
        #pragma unroll
        for (int c = 0; c < 5; ++c) {
            int jj = 2 * wo - 1 + c;
            bool ok = ((unsigned)ii < (unsigned)S) && ((unsigned)jj < (unsigned)S);
            p[r][c] = ok ? xs[(b * S + ii) * S + jj] : 0.0f;
        }
    }
    float best[8];
    #pragma unroll
    for (int co = 0; co < 8; ++co) best[co] = -1e30f;
    #pragma unroll
    for (int pi = 0; pi < 3; ++pi)
        #pragma unroll
        for (int pj = 0; pj < 3; ++pj) {
            if (mv[pi][pj] > 0.0f) {
                float acc[8];
                #pragma unroll
                for (int co = 0; co < 8; ++co) acc[co] = 0.0f;
                #pragma unroll
                for (int kh = 0; kh < 3; ++kh)
                    #pragma unroll
                    for (int kw = 0; kw < 3; ++kw) {
                        float x = p[pi + kh][pj + kw];
                        #pragma unroll
                        for (int co = 0; co < 8; ++co)
                            acc[co] = fmaf(x, w[(kh * 3 + kw) * 8 + co], acc[co]);
                    }
                #pragma unroll
                for (int co = 0; co < 8; ++co) best[co] = fmaxf(best[co], acc[co]);
            }
        }
    float4 o0 = make_float4(best[0], best[1], best[2], best[3]);
    float4 o1 = make_float4(best[4], best[5], best[6], best[7]);
    *(float4*)xp = o0;
    *(float4*)(xp + 4) = o1;
    m1[opix] = 1.0f;
}

// Fused conv: optionally bnrelu on input (h = mIn * relu(x*g+b)), conv, * mOut, [+ res].
// Thread per output pixel; blockIdx.y selects the COT-channel group (wave-uniform weights).
template <int K, int CIN, int COUT, int COT, bool BN, bool RES>
__global__ __launch_bounds__(256) void fconv_kernel(
    const float* __restrict__ in, const float* __restrict__ w,
    const float* __restrict__ g, const float* __restrict__ bbn,
    const float* __restrict__ mIn, const float* __restrict__ mOut,
    const float* __restrict__ res, float* __restrict__ out,
    int Hin, int Hout, int stride, int pad) {
    const int Win = Hin, Wout = Hout;
    int npix = BATCH * Hout * Wout;
    int opix = blockIdx.x * 256 + threadIdx.x;
    if (opix >= npix) return;
    int co0 = blockIdx.y * COT;
    int wo = opix % Wout;
    int t = opix / Wout;
    int ho = t % Hout;
    int b  = t / Hout;

    float mo = mOut[opix];
    float* op = out + (size_t)opix * COUT + co0;
    if (mo <= 0.0f) {
        #pragma unroll
        for (int j = 0; j < COT; j += 4) {
            float4 r4 = RES ? *(const float4*)(res + (size_t)opix * COUT + co0 + j)
                            : make_float4(0,0,0,0);
            *(float4*)(op + j) = r4;
        }
        return;
    }
    float acc[COT];
    #pragma unroll
    for (int j = 0; j < COT; ++j) acc[j] = 0.0f;

    #pragma unroll
    for (int kh = 0; kh < K; ++kh) {
        int ih = ho * stride + kh - pad;
        if ((unsigned)ih >= (unsigned)Hin) continue;
        #pragma unroll
        for (int kw = 0; kw < K; ++kw) {
            int iw = wo * stride + kw - pad;
            if ((unsigned)iw >= (unsigned)Win) continue;
            int ipix = (b * Hin + ih) * Win + iw;
            float mi = 1.0f;
            if (BN) { mi = mIn[ipix]; if (mi <= 0.0f) continue; }
            const float* ip = in + (size_t)ipix * CIN;
            const float* wp = w + (kh * K + kw) * CIN * COUT + co0;
            #pragma unroll
            for (int ci = 0; ci < CIN; ci += 4) {
                float4 xv = *(const float4*)(ip + ci);
                if (BN) {
                    xv.x = mi * fmaxf(fmaf(xv.x, g[ci],     bbn[ci]),     0.0f);
                    xv.y = mi * fmaxf(fmaf(xv.y, g[ci + 1], bbn[ci + 1]), 0.0f);
                    xv.z = mi * fmaxf(fmaf(xv.z, g[ci + 2], bbn[ci + 2]), 0.0f);
                    xv.w = mi * fmaxf(fmaf(xv.w, g[ci + 3], bbn[ci + 3]), 0.0f);
                }
                #pragma unroll
                for (int j = 0; j < COT; ++j) {
                    acc[j] = fmaf(xv.x, wp[(ci    ) * COUT + j], acc[j]);
                    acc[j] = fmaf(xv.y, wp[(ci + 1) * COUT + j], acc[j]);
                    acc[j] = fmaf(xv.z, wp[(ci + 2) * COUT + j], acc[j]);
                    acc[j] = fmaf(xv.w, wp[(ci + 3) * COUT + j], acc[j]);
                }
            }
        }
    }
    #pragma unroll
    for (int j = 0; j < COT; j += 4) {
        float4 o4;
        o4.x = acc[j] * mo; o4.y = acc[j+1] * mo; o4.z = acc[j+2] * mo; o4.w = acc[j+3] * mo;
        if (RES) {
            float4 r4 = *(const float4*)(res + (size_t)opix * COUT + co0 + j);
            o4.x += r4.x; o4.y += r4.y; o4.z += r4.z; o4.w += r4.w;
        }
        *(float4*)(op + j) = o4;
    }
}

__global__ void pool_kernel(const float* __restrict__ in, float* __restrict__ out,
                            int Hin, int Win, int Hout, int Wout, int win, int stride) {
    int tid = blockIdx.x * blockDim.x + threadIdx.x;
    int total = BATCH * Hout * Wout;
    if (tid >= total) return;
    int wo = tid % Wout;
    int p = tid / Wout;
    int ho = p % Hout;
    int b  = p / Hout;
    float mx = 0.0f;
    for (int i = 0; i < win; ++i)
        for (int j = 0; j < win; ++j)
            mx = fmaxf(mx, in[(b * Hin + ho * stride + i) * Win + wo * stride + j]);
    out[tid] = mx;
}

// Fused bnrelu(g17,b17) + flatten(NCHW) + linear. x: (B,8,8,64) NHWC pre-bn, m: (B,8,8).
__global__ __launch_bounds__(256) void linear_kernel(
    const float* __restrict__ x, const float* __restrict__ m,
    const float* __restrict__ g, const float* __restrict__ bbn,
    const float* __restrict__ wl, float* __restrict__ out) {
    int tid = blockIdx.x * 256 + threadIdx.x;
    if (tid >= BATCH * 100) return;
    int b = tid % BATCH;         // lanes span b -> wl loads wave-uniform
    int o = tid / BATCH;
    const float* wr = wl + o * 4096;
    float acc = 0.0f;
    for (int hw = 0; hw < 64; ++hw) {
        float mv = m[b * 64 + hw];
        if (mv <= 0.0f) continue;
        const float* xp = x + ((size_t)b * 64 + hw) * 64;
        float s = 0.0f;
        #pragma unroll 8
        for (int c = 0; c < 64; ++c) {
            float v = fmaxf(fmaf(xp[c], g[c], bbn[c]), 0.0f);
            s = fmaf(v, wr[c * 64 + hw], s);
        }
        acc += mv * s;
    }
    out[b * 100 + o] = acc;
}

template <int K, int CIN, int COUT, int COT, bool BN, bool RES>
static inline void fconv(hipStream_t s, const float* in, const float* w,
                         const float* g, const float* bbn,
                         const float* mIn, const float* mOut, const float* res,
                         float* out, int Hin, int Hout, int stride, int pad) {
    int npix = BATCH * Hout * Hout;
    dim3 grid((npix + 255) / 256, COUT / COT);
    fconv_kernel<K, CIN, COUT, COT, BN, RES><<<grid, 256, 0, s>>>(
        in, w, g, bbn, mIn, mOut, res, out, Hin, Hout, stride, pad);
}

extern "C" void kernel_launch(void* const* d_in, const int* in_sizes, int n_in,
                              void* d_out, int out_size, void* d_ws, size_t ws_size,
                              hipStream_t stream) {
    const int*   loc   = (const int*)d_in[0];
    const int*   bidx  = (const int*)d_in[1];
    const float* feat  = (const float*)d_in[2];
    const float* gamma = (const float*)d_in[3];
    const float* beta  = (const float*)d_in[4];
    const float* Wconv0 = (const float*)d_in[5];
    const float* Wc1a = (const float*)d_in[6];
    const float* Wc1b = (const float*)d_in[7];
    const float* Wc2a = (const float*)d_in[8];
    const float* Wc2b = (const float*)d_in[9];
    const float* Wc3a = (const float*)d_in[10];
    const float* Wc3b = (const float*)d_in[11];
    const float* Wc3r = (const float*)d_in[12];
    const float* Wc4a = (const float*)d_in[13];
    const float* Wc4b = (const float*)d_in[14];
    const float* Wc5a = (const float*)d_in[15];
    const float* Wc5b = (const float*)d_in[16];
    const float* Wc5r = (const float*)d_in[17];
    const float* Wc6a = (const float*)d_in[18];
    const float* Wc6b = (const float*)d_in[19];
    const float* Wc7a = (const float*)d_in[20];
    const float* Wc7b = (const float*)d_in[21];
    const float* Wc7r = (const float*)d_in[22];
    const float* Wc8a = (const float*)d_in[23];
    const float* Wc8b = (const float*)d_in[24];
    const float* Wlast = (const float*)d_in[25];
    const float* wlin  = (const float*)d_in[26];

    const size_t SZB = (size_t)BATCH * 103 * 103 * 8;  // 10,863,616 floats
    const size_t SZM = (size_t)BATCH * 103 * 103;      // 1,357,952 floats
    float* b0 = (float*)d_ws;
    float* b1 = b0 + SZB;
    float* b2 = b1 + SZB;
    float* m0 = b2 + SZB;
    float* m1 = m0 + SZM;

    const float* G[18];
    const float* Bt[18];
    for (int i = 0; i < 18; ++i) { G[i] = gamma + OFFS[i]; Bt[i] = beta + OFFS[i]; }

    auto pool = [&](const float* in, float* out, int Hin, int Hout, int win, int stride_) {
        int total = BATCH * Hout * Hout;
        pool_kernel<<<(total + 255) / 256, 256, 0, stream>>>(in, out, Hin, Hin, Hout, Hout, win, stride_);
    };

    // scatter into xs(b1), ms(b2)
    {
        int n = BATCH * S * S;               // 5,484,672 (divisible by 4)
        zero2_kernel<<<(n / 4 + 255) / 256, 256, 0, stream>>>((float4*)b1, (float4*)b2, n / 4);
        scatter_kernel<<<(NPTS + 255) / 256, 256, 0, stream>>>(loc, bidx, feat, b1, b2);
        int total = BATCH * 103 * 103;
        conv0_pool_kernel<<<(total + 255) / 256, 256, 0, stream>>>(b1, b2, Wconv0, b0, m0);
    }
    // x = b0 (103,103,8), mask = m0

    // c1 (stride1, 103, 8ch)
    fconv<3, 8, 8, 8, true, false>(stream, b0, Wc1a, G[0], Bt[0], m0, m0, nullptr, b1, 103, 103, 1, 1);
    fconv<3, 8, 8, 8, true, true >(stream, b1, Wc1b, G[1], Bt[1], m0, m0, b0,      b2, 103, 103, 1, 1);
    // c2
    fconv<3, 8, 8, 8, true, false>(stream, b2, Wc2a, G[2], Bt[2], m0, m0, nullptr, b0, 103, 103, 1, 1);
    fconv<3, 8, 8, 8, true, true >(stream, b0, Wc2b, G[3], Bt[3], m0, m0, b2,      b1, 103, 103, 1, 1);
    // c3 (stride2, 103->51, 8->16)
    pool(m0, m1, 103, 51, 3, 2);
    fconv<3, 8, 16, 8, false, false>(stream, b1, Wc3r, nullptr, nullptr, nullptr, m1, nullptr, b0, 103, 51, 2, 0);
    fconv<3, 8, 16, 8, true,  false>(stream, b1, Wc3a, G[4], Bt[4], m0, m1, nullptr, b2, 103, 51, 2, 0);
    fconv<3, 16, 16, 8, true, true >(stream, b2, Wc3b, G[5], Bt[5], m1, m1, b0,      b1, 51, 51, 1, 1);
    // x = b1, mask = m1
    // c4
    fconv<3, 16, 16, 8, true, false>(stream, b1, Wc4a, G[6], Bt[6], m1, m1, nullptr, b0, 51, 51, 1, 1);
    fconv<3, 16, 16, 8, true, true >(stream, b0, Wc4b, G[7], Bt[7], m1, m1, b1,      b2, 51, 51, 1, 1);
    // x = b2
    // c5 (stride2, 51->25, 16->24)
    pool(m1, m0, 51, 25, 3, 2);
    fconv<3, 16, 24, 8, false, false>(stream, b2, Wc5r, nullptr, nullptr, nullptr, m0, nullptr, b0, 51, 25, 2, 0);
    fconv<3, 16, 24, 8, true,  false>(stream, b2, Wc5a, G[8], Bt[8], m1, m0, nullptr, b1, 51, 25, 2, 0);
    fconv<3, 24, 24, 8, true,  true >(stream, b1, Wc5b, G[9], Bt[9], m0, m0, b0,      b2, 25, 25, 1, 1);
    // x = b2, mask = m0
    // c6
    fconv<3, 24, 24, 8, true, false>(stream, b2, Wc6a, G[10], Bt[10], m0, m0, nullptr, b0, 25, 25, 1, 1);
    fconv<3, 24, 24, 8, true, true >(stream, b0, Wc6b, G[11], Bt[11], m0, m0, b2,      b1, 25, 25, 1, 1);
    // x = b1
    // c7 (stride2, 25->12, 24->32)
    pool(m0, m1, 25, 12, 3, 2);
    fconv<3, 24, 32, 8, false, false>(stream, b1, Wc7r, nullptr, nullptr, nullptr, m1, nullptr, b0, 25, 12, 2, 0);
    fconv<3, 24, 32, 8, true,  false>(stream, b1, Wc7a, G[12], Bt[12], m0, m1, nullptr, b2, 25, 12, 2, 0);
    fconv<3, 32, 32, 8, true,  true >(stream, b2, Wc7b, G[13], Bt[13], m1, m1, b0,      b1, 12, 12, 1, 1);
    // x = b1, mask = m1
    // c8
    fconv<3, 32, 32, 8, true, false>(stream, b1, Wc8a, G[14], Bt[14], m1, m1, nullptr, b0, 12, 12, 1, 1);
    fconv<3, 32, 32, 8, true, true >(stream, b0, Wc8b, G[15], Bt[15], m1, m1, b1,      b2, 12, 12, 1, 1);
    // x = b2
    // tail
    pool(m1, m0, 12, 8, 5, 1);
    fconv<5, 32, 64, 4, true, false>(stream, b2, Wlast, G[16], Bt[16], m1, m0, nullptr, b0, 12, 8, 1, 0);
    linear_kernel<<<(BATCH * 100 + 255) / 256, 256, 0, stream>>>(b0, m0, G[17], Bt[17], wlin, (float*)d_out);
}